// Round 2
// baseline (1215.974 us; speedup 1.0000x reference)
//
#include <hip/hip_runtime.h>
#include <stdint.h>

#define BB   16
#define NN   65536
#define FF   32
#define KSEL 16384
#define SEG  64
#define EPSF 1e-10f

// ---- workspace layout (uint32 element offsets), ~42 MB ----
#define WS_MIN   0
#define WS_PART  256                         // [SEG][256][512] u32 partial hists
#define WS_HIST  (WS_PART + SEG*256*512)     // [256][512] reduced hist
#define WS_PREF  (WS_HIST + 256*512)         // [512] prefix (8b after r0, 16b after r1)
#define WS_REM   (WS_PREF + 512)             // [512] remaining rank within bucket
#define WS_EQC   (WS_REM + 512)              // [512] candidate counters
#define WS_EQL   (WS_EQC + 512)              // [512][2048] u64 (skey<<32 | ~n)

__device__ __forceinline__ uint32_t fkey(float s) {
    uint32_t u = __float_as_uint(s);
    return (u & 0x80000000u) ? ~u : (u | 0x80000000u);
}

// ---- hist pass on RAW x keys; PASS 0 also computes global min|x| ----
template <int PASS>
__global__ __launch_bounds__(512) void khist(const float* __restrict__ xf, uint32_t* __restrict__ ws) {
    __shared__ uint32_t lh[256 * 33];
    __shared__ uint32_t lpref[32];
    __shared__ uint32_t rmin[512];
    const int b = blockIdx.x >> 6;
    const int s = blockIdx.x & 63;
    const int tid = threadIdx.x;
    for (int i = tid; i < 256 * 33; i += 512) lh[i] = 0;
    if (PASS == 1 && tid < 32) lpref[tid] = ws[WS_PREF + b * 32 + tid];
    __syncthreads();
    const float4* x4 = (const float4*)xf + (size_t)b * (NN * FF / 4) + (size_t)s * 8192;
    uint32_t mreg = 0xFFFFFFFFu;
    float4 cur = x4[tid];
#pragma unroll
    for (int i = 0; i < 16; ++i) {
        float4 nxt = cur;
        if (i < 15) nxt = x4[(i + 1) * 512 + tid];
        const int e = i * 512 + tid;
        const int fb = (e & 7) * 4;
        float vv[4] = {cur.x, cur.y, cur.z, cur.w};
#pragma unroll
        for (int j = 0; j < 4; ++j) {
            uint32_t u = __float_as_uint(vv[j]);
            if (PASS == 0) { uint32_t a = u & 0x7FFFFFFFu; mreg = a < mreg ? a : mreg; }
            uint32_t key = (u & 0x80000000u) ? ~u : (u | 0x80000000u);
            if (PASS == 0) {
                atomicAdd(&lh[(key >> 24) * 33 + fb + j], 1u);
            } else {
                if ((key >> 24) == lpref[fb + j])
                    atomicAdd(&lh[((key >> 16) & 255u) * 33 + fb + j], 1u);
            }
        }
        cur = nxt;
    }
    if (PASS == 0) {
        rmin[tid] = mreg;
        __syncthreads();
        for (int off = 256; off > 0; off >>= 1) {
            if (tid < off) { uint32_t o = rmin[tid + off]; if (o < rmin[tid]) rmin[tid] = o; }
            __syncthreads();
        }
        if (tid == 0) atomicMin(&ws[WS_MIN], rmin[0]);
    } else {
        __syncthreads();
    }
    uint32_t* part = ws + WS_PART;
    for (int k = tid; k < 8192; k += 512) {
        int f = k & 31, bin = k >> 5;
        part[((size_t)s * 256 + bin) * 512 + b * 32 + f] = lh[bin * 33 + f];
    }
}

// ---- reduce partials over segments ----
__global__ __launch_bounds__(256) void kreduce(uint32_t* __restrict__ ws) {
    const int bin = blockIdx.x;
    const uint32_t* part = ws + WS_PART;
    uint32_t* hist = ws + WS_HIST;
    for (int col = threadIdx.x; col < 512; col += 256) {
        uint32_t sum = 0;
#pragma unroll 8
        for (int s = 0; s < SEG; ++s) sum += part[((size_t)s * 256 + bin) * 512 + col];
        hist[bin * 512 + col] = sum;
    }
}

// ---- per-column: find bucket containing the r-th largest ----
template <int PASS>
__global__ void kresolve(uint32_t* __restrict__ ws) {
    const int col = blockIdx.x * 128 + threadIdx.x;
    if (col >= 512) return;
    const uint32_t* hist = ws + WS_HIST;
    uint32_t r = (PASS == 0) ? (uint32_t)KSEL : ws[WS_REM + col];
    uint32_t cum = 0, v = 0;
    for (int bin = 255; bin >= 0; --bin) {
        uint32_t h = hist[bin * 512 + col];
        if (cum + h >= r) { v = (uint32_t)bin; break; }
        cum += h;
    }
    r -= cum;
    if (PASS == 0) {
        ws[WS_PREF + col] = v;
        ws[WS_REM + col] = r;
    } else {
        ws[WS_PREF + col] = (ws[WS_PREF + col] << 8) | v;
        ws[WS_REM + col] = r;
        ws[WS_EQC + col] = 0;
    }
}

// ---- mark: write updated + masked; collect 16-bit-bucket candidates ----
__global__ __launch_bounds__(256) void kmark(const float* __restrict__ xf, const float* __restrict__ mask,
                                             uint32_t* __restrict__ ws, float* __restrict__ upd,
                                             float* __restrict__ omask) {
    __shared__ uint32_t lp[32];
    __shared__ float lmin;
    const int b = blockIdx.x >> 11;
    const int blk = blockIdx.x & 2047;
    const int tid = threadIdx.x;
    if (tid < 32) lp[tid] = ws[WS_PREF + b * 32 + tid];
    if (tid == 0) lmin = __uint_as_float(ws[WS_MIN]);
    __syncthreads();
    const int e = blk * 256 + tid;
    const float4 v = ((const float4*)xf)[(size_t)b * 524288 + e];
    const int n = e >> 3;
    const int fb = (e & 7) * 4;
    const float mn = lmin;
    float vv[4] = {v.x, v.y, v.z, v.w};
    bool sel = false;
#pragma unroll
    for (int j = 0; j < 4; ++j) {
        uint32_t key = fkey(vv[j]);
        uint32_t k16 = key >> 16;
        uint32_t p = lp[fb + j];
        if (k16 > p) {
            sel = true;
        } else if (k16 == p) {
            float mk = mask[(size_t)b * NN + n];
            float sv = ((vv[j] + mn) + EPSF) * mk;
            uint32_t skey = fkey(sv);
            uint32_t col = (uint32_t)(b * 32 + fb + j);
            uint32_t idx = atomicAdd(&ws[WS_EQC + col], 1u);
            if (idx < 2048u) {
                uint64_t* lst = (uint64_t*)(ws + WS_EQL);
                lst[(size_t)col * 2048 + idx] = ((uint64_t)skey << 32) | (uint32_t)(~(uint32_t)n);
            }
        }
    }
    unsigned long long bal = __ballot(sel);
    int lane = tid & 63;
    uint32_t grp = (uint32_t)(bal >> (lane & 56)) & 0xFFu;
    float u1 = grp ? 1.0f : 0.0f;
    float4 o;
    o.x = vv[0] * u1; o.y = vv[1] * u1; o.z = vv[2] * u1; o.w = vv[3] * u1;
    ((float4*)omask)[(size_t)b * 524288 + e] = o;
    if ((tid & 7) == 0) upd[(size_t)b * NN + n] = u1;
}

// ---- fixup: take exactly r candidates per column by (s desc, idx asc) ----
__global__ void kfix(const float* __restrict__ xf, uint32_t* __restrict__ ws,
                     float* __restrict__ upd, float* __restrict__ omask) {
    const int col = blockIdx.x * 128 + threadIdx.x;
    if (col >= 512) return;
    uint32_t r = ws[WS_REM + col];
    uint32_t cnt = ws[WS_EQC + col];
    if (cnt > 2048u) cnt = 2048u;
    if (r > cnt) r = cnt;
    uint64_t* lst = (uint64_t*)(ws + WS_EQL) + (size_t)col * 2048;
    const int b = col >> 5;
    for (uint32_t t = 0; t < r; ++t) {
        uint64_t best = 0; uint32_t bi = 0;
        for (uint32_t i = 0; i < cnt; ++i) {
            uint64_t val = lst[i];
            if (val > best) { best = val; bi = i; }
        }
        lst[bi] = 0;
        uint32_t n = ~(uint32_t)best;
        upd[(size_t)b * NN + n] = 1.0f;
        const float* xr = xf + ((size_t)b * NN + n) * FF;
        float* orow = omask + ((size_t)b * NN + n) * FF;
        for (int f = 0; f < FF; ++f) orow[f] = xr[f];
    }
}

extern "C" void kernel_launch(void* const* d_in, const int* in_sizes, int n_in,
                              void* d_out, int out_size, void* d_ws, size_t ws_size,
                              hipStream_t stream) {
    const float* x = (const float*)d_in[0];
    const float* mask = (const float*)d_in[1];
    float* upd = (float*)d_out;                       // (B,N,1)
    float* omask = (float*)d_out + (size_t)BB * NN;   // (B,N,F)
    uint32_t* ws = (uint32_t*)d_ws;

    hipMemsetAsync(d_ws, 0xFF, 4, stream);            // min := +inf-ish

    khist<0><<<BB * SEG, 512, 0, stream>>>(x, ws);    // fused min + top-8 hist
    kreduce<<<256, 256, 0, stream>>>(ws);
    kresolve<0><<<4, 128, 0, stream>>>(ws);

    khist<1><<<BB * SEG, 512, 0, stream>>>(x, ws);    // next-8 hist (filtered)
    kreduce<<<256, 256, 0, stream>>>(ws);
    kresolve<1><<<4, 128, 0, stream>>>(ws);

    kmark<<<BB * 2048, 256, 0, stream>>>(x, mask, ws, upd, omask);
    kfix<<<4, 128, 0, stream>>>(x, ws, upd, omask);
}

// Round 3
// 291.539 us; speedup vs baseline: 4.1709x; 4.1709x over previous
//
#include <hip/hip_runtime.h>
#include <stdint.h>

#define BB   16
#define NN   65536
#define FF   32
#define KSEL 16384
#define SEG  64
#define EPSF 1e-10f

// ---- workspace layout (uint32 element offsets), ~42 MB ----
#define WS_MIN   0
#define WS_PART  256                         // [SEG][256][512] u32 partial hists
#define WS_HIST  (WS_PART + SEG*256*512)     // [256][512] reduced hist
#define WS_PREF  (WS_HIST + 256*512)         // [512] prefix (8b after r0, 16b after r1)
#define WS_REM   (WS_PREF + 512)             // [512] remaining rank within bucket
#define WS_EQC   (WS_REM + 512)              // [512] candidate counters
#define WS_EQL   (WS_EQC + 512)              // [512][2048] u64 (skey<<32 | ~n)

__device__ __forceinline__ uint32_t fkey(float s) {
    uint32_t u = __float_as_uint(s);
    return (u & 0x80000000u) ? ~u : (u | 0x80000000u);
}

// ---- hist pass on RAW x keys; PASS 0 also computes global min|x| ----
template <int PASS>
__global__ __launch_bounds__(512) void khist(const float* __restrict__ xf, uint32_t* __restrict__ ws) {
    __shared__ uint32_t lh[256 * 33];
    __shared__ uint32_t lpref[32];
    __shared__ uint32_t rmin[512];
    const int b = blockIdx.x >> 6;
    const int s = blockIdx.x & 63;
    const int tid = threadIdx.x;
    for (int i = tid; i < 256 * 33; i += 512) lh[i] = 0;
    if (PASS == 1 && tid < 32) lpref[tid] = ws[WS_PREF + b * 32 + tid];
    __syncthreads();
    const float4* x4 = (const float4*)xf + (size_t)b * (NN * FF / 4) + (size_t)s * 8192;
    uint32_t mreg = 0xFFFFFFFFu;
    float4 cur = x4[tid];
#pragma unroll
    for (int i = 0; i < 16; ++i) {
        float4 nxt = cur;
        if (i < 15) nxt = x4[(i + 1) * 512 + tid];
        const int e = i * 512 + tid;
        const int fb = (e & 7) * 4;
        float vv[4] = {cur.x, cur.y, cur.z, cur.w};
#pragma unroll
        for (int j = 0; j < 4; ++j) {
            uint32_t u = __float_as_uint(vv[j]);
            if (PASS == 0) { uint32_t a = u & 0x7FFFFFFFu; mreg = a < mreg ? a : mreg; }
            uint32_t key = (u & 0x80000000u) ? ~u : (u | 0x80000000u);
            if (PASS == 0) {
                atomicAdd(&lh[(key >> 24) * 33 + fb + j], 1u);
            } else {
                if ((key >> 24) == lpref[fb + j])
                    atomicAdd(&lh[((key >> 16) & 255u) * 33 + fb + j], 1u);
            }
        }
        cur = nxt;
    }
    if (PASS == 0) {
        rmin[tid] = mreg;
        __syncthreads();
        for (int off = 256; off > 0; off >>= 1) {
            if (tid < off) { uint32_t o = rmin[tid + off]; if (o < rmin[tid]) rmin[tid] = o; }
            __syncthreads();
        }
        if (tid == 0) atomicMin(&ws[WS_MIN], rmin[0]);
    } else {
        __syncthreads();
    }
    uint32_t* part = ws + WS_PART;
    for (int k = tid; k < 8192; k += 512) {
        int f = k & 31, bin = k >> 5;
        part[((size_t)s * 256 + bin) * 512 + b * 32 + f] = lh[bin * 33 + f];
    }
}

// ---- reduce partials over segments ----
__global__ __launch_bounds__(256) void kreduce(uint32_t* __restrict__ ws) {
    const int bin = blockIdx.x;
    const uint32_t* part = ws + WS_PART;
    uint32_t* hist = ws + WS_HIST;
    for (int col = threadIdx.x; col < 512; col += 256) {
        uint32_t sum = 0;
#pragma unroll 8
        for (int s = 0; s < SEG; ++s) sum += part[((size_t)s * 256 + bin) * 512 + col];
        hist[bin * 512 + col] = sum;
    }
}

// ---- per-column: find bucket containing the r-th largest ----
template <int PASS>
__global__ void kresolve(uint32_t* __restrict__ ws) {
    const int col = blockIdx.x * 128 + threadIdx.x;
    if (col >= 512) return;
    const uint32_t* hist = ws + WS_HIST;
    uint32_t r = (PASS == 0) ? (uint32_t)KSEL : ws[WS_REM + col];
    uint32_t cum = 0, v = 0;
    for (int bin = 255; bin >= 0; --bin) {
        uint32_t h = hist[bin * 512 + col];
        if (cum + h >= r) { v = (uint32_t)bin; break; }
        cum += h;
    }
    r -= cum;
    if (PASS == 0) {
        ws[WS_PREF + col] = v;
        ws[WS_REM + col] = r;
    } else {
        ws[WS_PREF + col] = (ws[WS_PREF + col] << 8) | v;
        ws[WS_REM + col] = r;
        ws[WS_EQC + col] = 0;
    }
}

// ---- mark: write updated + masked; collect 16-bit-bucket candidates ----
__global__ __launch_bounds__(256) void kmark(const float* __restrict__ xf, const float* __restrict__ mask,
                                             uint32_t* __restrict__ ws, float* __restrict__ upd,
                                             float* __restrict__ omask) {
    __shared__ uint32_t lp[32];
    __shared__ float lmin;
    const int b = blockIdx.x >> 11;
    const int blk = blockIdx.x & 2047;
    const int tid = threadIdx.x;
    if (tid < 32) lp[tid] = ws[WS_PREF + b * 32 + tid];
    if (tid == 0) lmin = __uint_as_float(ws[WS_MIN]);
    __syncthreads();
    const int e = blk * 256 + tid;
    const float4 v = ((const float4*)xf)[(size_t)b * 524288 + e];
    const int n = e >> 3;
    const int fb = (e & 7) * 4;
    const float mn = lmin;
    float vv[4] = {v.x, v.y, v.z, v.w};
    bool sel = false;
#pragma unroll
    for (int j = 0; j < 4; ++j) {
        uint32_t key = fkey(vv[j]);
        uint32_t k16 = key >> 16;
        uint32_t p = lp[fb + j];
        if (k16 > p) {
            sel = true;
        } else if (k16 == p) {
            float mk = mask[(size_t)b * NN + n];
            float sv = ((vv[j] + mn) + EPSF) * mk;
            uint32_t skey = fkey(sv);
            uint32_t col = (uint32_t)(b * 32 + fb + j);
            uint32_t idx = atomicAdd(&ws[WS_EQC + col], 1u);
            if (idx < 2048u) {
                uint64_t* lst = (uint64_t*)(ws + WS_EQL);
                lst[(size_t)col * 2048 + idx] = ((uint64_t)skey << 32) | (uint32_t)(~(uint32_t)n);
            }
        }
    }
    unsigned long long bal = __ballot(sel);
    int lane = tid & 63;
    uint32_t grp = (uint32_t)(bal >> (lane & 56)) & 0xFFu;
    float u1 = grp ? 1.0f : 0.0f;
    float4 o;
    o.x = vv[0] * u1; o.y = vv[1] * u1; o.z = vv[2] * u1; o.w = vv[3] * u1;
    ((float4*)omask)[(size_t)b * 524288 + e] = o;
    if ((tid & 7) == 0) upd[(size_t)b * NN + n] = u1;
}

// ---- fixup: parallel rank-select — one WG per column, candidates in LDS ----
__global__ __launch_bounds__(256) void kfix(const float* __restrict__ xf, uint32_t* __restrict__ ws,
                                            float* __restrict__ upd, float* __restrict__ omask) {
    __shared__ uint64_t cand[2048];
    const int col = blockIdx.x;
    uint32_t r = ws[WS_REM + col];
    uint32_t cnt = ws[WS_EQC + col];
    if (cnt > 2048u) cnt = 2048u;
    if (r > cnt) r = cnt;
    const uint64_t* lst = (const uint64_t*)(ws + WS_EQL) + (size_t)col * 2048;
    for (uint32_t i = threadIdx.x; i < cnt; i += 256) cand[i] = lst[i];
    __syncthreads();
    const int b = col >> 5;
    for (uint32_t i = threadIdx.x; i < cnt; i += 256) {
        const uint64_t key = cand[i];
        uint32_t rank = 0;
        for (uint32_t j = 0; j < cnt; ++j) rank += (cand[j] > key) ? 1u : 0u;
        if (rank < r) {
            uint32_t n = ~(uint32_t)key;
            upd[(size_t)b * NN + n] = 1.0f;
            const float4* xr = (const float4*)(xf + ((size_t)b * NN + n) * FF);
            float4* orow = (float4*)(omask + ((size_t)b * NN + n) * FF);
#pragma unroll
            for (int f = 0; f < 8; ++f) orow[f] = xr[f];
        }
    }
}

extern "C" void kernel_launch(void* const* d_in, const int* in_sizes, int n_in,
                              void* d_out, int out_size, void* d_ws, size_t ws_size,
                              hipStream_t stream) {
    const float* x = (const float*)d_in[0];
    const float* mask = (const float*)d_in[1];
    float* upd = (float*)d_out;                       // (B,N,1)
    float* omask = (float*)d_out + (size_t)BB * NN;   // (B,N,F)
    uint32_t* ws = (uint32_t*)d_ws;

    hipMemsetAsync(d_ws, 0xFF, 4, stream);            // min := +inf-ish

    khist<0><<<BB * SEG, 512, 0, stream>>>(x, ws);    // fused min + top-8 hist
    kreduce<<<256, 256, 0, stream>>>(ws);
    kresolve<0><<<4, 128, 0, stream>>>(ws);

    khist<1><<<BB * SEG, 512, 0, stream>>>(x, ws);    // next-8 hist (filtered)
    kreduce<<<256, 256, 0, stream>>>(ws);
    kresolve<1><<<4, 128, 0, stream>>>(ws);

    kmark<<<BB * 2048, 256, 0, stream>>>(x, mask, ws, upd, omask);
    kfix<<<512, 256, 0, stream>>>(x, ws, upd, omask);
}

// Round 4
// 240.976 us; speedup vs baseline: 5.0460x; 1.2098x over previous
//
#include <hip/hip_runtime.h>
#include <stdint.h>

#define BB   16
#define NN   65536
#define FF   32
#define KSEL 16384
#define SEG  64
#define EPSF 1e-10f

typedef float f4v __attribute__((ext_vector_type(4)));

// ---- workspace layout (uint32 element offsets), ~42 MB ----
#define WS_MIN   0
#define WS_PART  256                         // [SEG][256][512] u32 partial hists
#define WS_HIST  (WS_PART + SEG*256*512)     // [256][512] reduced hist
#define WS_PREF  (WS_HIST + 256*512)         // [512] prefix (8b after r0, 16b after r1)
#define WS_REM   (WS_PREF + 512)             // [512] remaining rank within bucket
#define WS_EQC   (WS_REM + 512)              // [512] candidate counters
#define WS_EQL   (WS_EQC + 512)              // [512][2048] u64 (skey<<32 | ~n)

__device__ __forceinline__ uint32_t fkey(float s) {
    uint32_t u = __float_as_uint(s);
    return (u & 0x80000000u) ? ~u : (u | 0x80000000u);
}

// ---- hist pass on RAW x keys; PASS 0 also computes global min|x| ----
// 4-deep independent load clusters for MLP.
template <int PASS>
__global__ __launch_bounds__(512) void khist(const float* __restrict__ xf, uint32_t* __restrict__ ws) {
    __shared__ uint32_t lh[256 * 33];
    __shared__ uint32_t lpref[32];
    __shared__ uint32_t rmin[512];
    const int b = blockIdx.x >> 6;
    const int s = blockIdx.x & 63;
    const int tid = threadIdx.x;
    for (int i = tid; i < 256 * 33; i += 512) lh[i] = 0;
    if (PASS == 1 && tid < 32) lpref[tid] = ws[WS_PREF + b * 32 + tid];
    __syncthreads();
    const float4* x4 = (const float4*)xf + (size_t)b * (NN * FF / 4) + (size_t)s * 8192;
    uint32_t mreg = 0xFFFFFFFFu;

    auto proc = [&](float4 v, int e) {
        const int fb = (e & 7) * 4;
        float vv[4] = {v.x, v.y, v.z, v.w};
#pragma unroll
        for (int j = 0; j < 4; ++j) {
            uint32_t u = __float_as_uint(vv[j]);
            if (PASS == 0) { uint32_t a = u & 0x7FFFFFFFu; mreg = a < mreg ? a : mreg; }
            uint32_t key = (u & 0x80000000u) ? ~u : (u | 0x80000000u);
            if (PASS == 0) {
                atomicAdd(&lh[(key >> 24) * 33 + fb + j], 1u);
            } else {
                if ((key >> 24) == lpref[fb + j])
                    atomicAdd(&lh[((key >> 16) & 255u) * 33 + fb + j], 1u);
            }
        }
    };

#pragma unroll
    for (int c = 0; c < 4; ++c) {
        const int eb = c * 2048;
        float4 v0 = x4[eb + tid];
        float4 v1 = x4[eb + 512 + tid];
        float4 v2 = x4[eb + 1024 + tid];
        float4 v3 = x4[eb + 1536 + tid];
        proc(v0, eb + tid);
        proc(v1, eb + 512 + tid);
        proc(v2, eb + 1024 + tid);
        proc(v3, eb + 1536 + tid);
    }

    if (PASS == 0) {
        rmin[tid] = mreg;
        __syncthreads();
        for (int off = 256; off > 0; off >>= 1) {
            if (tid < off) { uint32_t o = rmin[tid + off]; if (o < rmin[tid]) rmin[tid] = o; }
            __syncthreads();
        }
        if (tid == 0) atomicMin(&ws[WS_MIN], rmin[0]);
    } else {
        __syncthreads();
    }
    uint32_t* part = ws + WS_PART;
    for (int k = tid; k < 8192; k += 512) {
        int f = k & 31, bin = k >> 5;
        part[((size_t)s * 256 + bin) * 512 + b * 32 + f] = lh[bin * 33 + f];
    }
}

// ---- reduce partials over segments ----
__global__ __launch_bounds__(256) void kreduce(uint32_t* __restrict__ ws) {
    const int bin = blockIdx.x;
    const uint32_t* part = ws + WS_PART;
    uint32_t* hist = ws + WS_HIST;
    for (int col = threadIdx.x; col < 512; col += 256) {
        uint32_t sum = 0;
#pragma unroll 8
        for (int s = 0; s < SEG; ++s) sum += part[((size_t)s * 256 + bin) * 512 + col];
        hist[bin * 512 + col] = sum;
    }
}

// ---- per-column: find bucket containing the r-th largest (1 block, 512 thr) ----
template <int PASS>
__global__ __launch_bounds__(512) void kresolve(uint32_t* __restrict__ ws) {
    const int col = threadIdx.x;
    const uint32_t* hist = ws + WS_HIST;
    uint32_t r = (PASS == 0) ? (uint32_t)KSEL : ws[WS_REM + col];
    uint32_t cum = 0, v = 0;
    for (int bin = 255; bin >= 0; --bin) {
        uint32_t h = hist[bin * 512 + col];
        if (cum + h >= r) { v = (uint32_t)bin; break; }
        cum += h;
    }
    r -= cum;
    if (PASS == 0) {
        ws[WS_PREF + col] = v;
        ws[WS_REM + col] = r;
    } else {
        ws[WS_PREF + col] = (ws[WS_PREF + col] << 8) | v;
        ws[WS_REM + col] = r;
        ws[WS_EQC + col] = 0;
    }
}

// ---- mark: 8 float4/thread (MLP 8); write updated + masked; collect candidates ----
__global__ __launch_bounds__(256) void kmark(const float* __restrict__ xf, const float* __restrict__ mask,
                                             uint32_t* __restrict__ ws, float* __restrict__ upd,
                                             float* __restrict__ omask) {
    __shared__ uint32_t lp[32];
    __shared__ float lmin;
    const int b = blockIdx.x >> 8;      // 256 blocks per batch
    const int blk = blockIdx.x & 255;
    const int tid = threadIdx.x;
    if (tid < 32) lp[tid] = ws[WS_PREF + b * 32 + tid];
    if (tid == 0) lmin = __uint_as_float(ws[WS_MIN]);
    __syncthreads();
    const size_t bbase = (size_t)b * 524288;
    const float4* x4 = (const float4*)xf + bbase;
    f4v* o4 = (f4v*)omask + bbase;
    const int ebase = blk * 2048 + tid;
    float4 v[8];
#pragma unroll
    for (int i = 0; i < 8; ++i) v[i] = x4[ebase + i * 256];
    const float mn = lmin;
    const int lane = tid & 63;
#pragma unroll
    for (int i = 0; i < 8; ++i) {
        const int e = ebase + i * 256;
        const int n = e >> 3;
        const int fb = (e & 7) * 4;
        float vv[4] = {v[i].x, v[i].y, v[i].z, v[i].w};
        bool sel = false;
#pragma unroll
        for (int j = 0; j < 4; ++j) {
            uint32_t key = fkey(vv[j]);
            uint32_t k16 = key >> 16;
            uint32_t p = lp[fb + j];
            if (k16 > p) {
                sel = true;
            } else if (k16 == p) {
                float mk = mask[(size_t)b * NN + n];
                float sv = ((vv[j] + mn) + EPSF) * mk;
                uint32_t skey = fkey(sv);
                uint32_t col = (uint32_t)(b * 32 + fb + j);
                uint32_t idx = atomicAdd(&ws[WS_EQC + col], 1u);
                if (idx < 2048u) {
                    uint64_t* lst = (uint64_t*)(ws + WS_EQL);
                    lst[(size_t)col * 2048 + idx] = ((uint64_t)skey << 32) | (uint32_t)(~(uint32_t)n);
                }
            }
        }
        unsigned long long bal = __ballot(sel);
        uint32_t grp = (uint32_t)(bal >> (lane & 56)) & 0xFFu;
        float u1 = grp ? 1.0f : 0.0f;
        f4v o;
        o.x = vv[0] * u1; o.y = vv[1] * u1; o.z = vv[2] * u1; o.w = vv[3] * u1;
        __builtin_nontemporal_store(o, &o4[e]);
        if ((tid & 7) == 0) __builtin_nontemporal_store(u1, &upd[(size_t)b * NN + n]);
    }
}

// ---- fixup: parallel rank-select — one WG per column, candidates in LDS ----
__global__ __launch_bounds__(256) void kfix(const float* __restrict__ xf, uint32_t* __restrict__ ws,
                                            float* __restrict__ upd, float* __restrict__ omask) {
    __shared__ uint64_t cand[2048];
    const int col = blockIdx.x;
    uint32_t r = ws[WS_REM + col];
    uint32_t cnt = ws[WS_EQC + col];
    if (cnt > 2048u) cnt = 2048u;
    if (r > cnt) r = cnt;
    const uint64_t* lst = (const uint64_t*)(ws + WS_EQL) + (size_t)col * 2048;
    for (uint32_t i = threadIdx.x; i < cnt; i += 256) cand[i] = lst[i];
    __syncthreads();
    const int b = col >> 5;
    for (uint32_t i = threadIdx.x; i < cnt; i += 256) {
        const uint64_t key = cand[i];
        uint32_t rank = 0;
        for (uint32_t j = 0; j < cnt; ++j) rank += (cand[j] > key) ? 1u : 0u;
        if (rank < r) {
            uint32_t n = ~(uint32_t)key;
            upd[(size_t)b * NN + n] = 1.0f;
            const float4* xr = (const float4*)(xf + ((size_t)b * NN + n) * FF);
            float4* orow = (float4*)(omask + ((size_t)b * NN + n) * FF);
#pragma unroll
            for (int f = 0; f < 8; ++f) orow[f] = xr[f];
        }
    }
}

extern "C" void kernel_launch(void* const* d_in, const int* in_sizes, int n_in,
                              void* d_out, int out_size, void* d_ws, size_t ws_size,
                              hipStream_t stream) {
    const float* x = (const float*)d_in[0];
    const float* mask = (const float*)d_in[1];
    float* upd = (float*)d_out;                       // (B,N,1)
    float* omask = (float*)d_out + (size_t)BB * NN;   // (B,N,F)
    uint32_t* ws = (uint32_t*)d_ws;

    hipMemsetAsync(d_ws, 0xFF, 4, stream);            // min := +inf-ish

    khist<0><<<BB * SEG, 512, 0, stream>>>(x, ws);    // fused min + top-8 hist
    kreduce<<<256, 256, 0, stream>>>(ws);
    kresolve<0><<<1, 512, 0, stream>>>(ws);

    khist<1><<<BB * SEG, 512, 0, stream>>>(x, ws);    // next-8 hist (filtered)
    kreduce<<<256, 256, 0, stream>>>(ws);
    kresolve<1><<<1, 512, 0, stream>>>(ws);

    kmark<<<BB * 256, 256, 0, stream>>>(x, mask, ws, upd, omask);
    kfix<<<512, 256, 0, stream>>>(x, ws, upd, omask);
}